// Round 8
// baseline (41.675 us; speedup 1.0000x reference)
//
#include <hip/hip_runtime.h>
#include <stdint.h>

// ---------------- problem constants ----------------
#define DIM   64
#define VPA   65                      // voxels per axis = DIM+1
#define NVOX  (VPA*VPA*VPA)           // 274625
#define NTET  (6*NVOX)                // 1647750 tets (M)
// output is FLOAT32, concatenated flat: verts | tris | mask (f32 element offsets)
#define TRIS_OFF_F  29659500          // NTET*18
#define MASK_OFF_F  39546000          // NTET*18 + NTET*6
#define NTPB 256                      // tets per block (= threads per block)

// native vector type accepted by __builtin_nontemporal_store
typedef float f4v __attribute__((ext_vector_type(4)));

// marching-tets case table, nibble packed: slot s in bits [4s,4s+4), 0xF == -1
__constant__ unsigned int c_TRIP[16] = {
    0xFFFFFFu, // 0: none
    0xFFF210u, // 1: 0,1,2
    0xFFF340u, // 2: 0,4,3
    0x341421u, // 3: 1,2,4, 1,4,3
    0xFFF531u, // 4: 1,3,5
    0x250530u, // 5: 0,3,5, 0,5,2
    0x150540u, // 6: 0,4,5, 0,5,1
    0xFFF542u, // 7: 2,4,5
    0xFFF452u, // 8: 2,5,4
    0x510450u, // 9: 0,5,4, 0,1,5
    0x520350u, //10: 0,5,3, 0,2,5
    0xFFF351u, //11: 1,5,3
    0x431241u, //12: 1,4,2, 1,3,4
    0xFFF430u, //13: 0,3,4
    0xFFF120u, //14: 0,2,1
    0xFFFFFFu  //15: none
};
// tet corner ids (voxel corner 0..7), nibble packed per tet (TETS rows)
__constant__ unsigned short c_TETP[6] = {
    0x6210u, 0x6320u, 0x6730u, 0x6470u, 0x6540u, 0x6150u
};
// edge endpoint tables, nibble packed: EDGE_A={0,0,0,1,1,2}, EDGE_B={1,2,3,2,3,3}
#define EA_PACK 0x211000u
#define EB_PACK 0x332321u
// voxel corner offset bitmasks: x set for corners {1,2,5,6}; y {2,3,6,7}; z {4,5,6,7}
#define OFFX_MASK 0x66u
#define OFFY_MASK 0xCCu
#define OFFZ_MASK 0xF0u

__global__ __launch_bounds__(256) void mc_kernel(
    const float* __restrict__ grid,
    const float* __restrict__ deform,
    float* __restrict__ out)
{
    // AoS staging: ldsv[t*18 + j] == output float (base*18 + t*18 + j)
    __shared__ __align__(16) float  ldsv[NTPB * 18];   // 18432 B
    __shared__ __align__(16) float2 ldsm[NTPB];        //  2048 B

    const int tid  = threadIdx.x;
    const int base = blockIdx.x * NTPB;
    const int m    = base + tid;
    const int nv   = min(NTPB, NTET - base);   // valid tets in this block
    const bool full = (nv == NTPB);            // block-uniform

    if (m < NTET) {
        int v = m / 6;
        int t = m - v * 6;
        int iz = v % VPA;
        int tmp = v / VPA;
        int iy = tmp % VPA;
        int ix = tmp / VPA;

        // gather 4 tet corners: value + deformed position
        float tv[4];
        float tpx[4], tpy[4], tpz[4];
        unsigned int tet = c_TETP[t];
        #pragma unroll
        for (int c = 0; c < 4; ++c) {
            unsigned int corner = (tet >> (4 * c)) & 0xFu;
            int px = ix + (int)((OFFX_MASK >> corner) & 1u);
            int py = iy + (int)((OFFY_MASK >> corner) & 1u);
            int pz = iz + (int)((OFFZ_MASK >> corner) & 1u);
            // padded coords px,py,pz in [0,65]; interior iff 1..64
            bool interior = ((unsigned)(px - 1) < (unsigned)DIM) &
                            ((unsigned)(py - 1) < (unsigned)DIM) &
                            ((unsigned)(pz - 1) < (unsigned)DIM);
            float val = 1.0f;               // iso + 1 pad value
            float dx = 0.f, dy = 0.f, dz = 0.f;
            if (interior) {
                int gi = ((px - 1) * DIM + (py - 1)) * DIM + (pz - 1);
                val = grid[gi];
                const float* d = deform + 3 * (size_t)gi;
                dx = d[0]; dy = d[1]; dz = d[2];
            }
            tv[c]  = val;
            tpx[c] = (float)px + dx;
            tpy[c] = (float)py + dy;
            tpz[c] = (float)pz + dz;
        }

        int code = (tv[0] > 0.f ? 1 : 0) | (tv[1] > 0.f ? 2 : 0) |
                   (tv[2] > 0.f ? 4 : 0) | (tv[3] > 0.f ? 8 : 0);
        unsigned int tri = c_TRIP[code];

        float verts[18];
        bool mask0 = false, mask1 = false;
        #pragma unroll
        for (int s = 0; s < 6; ++s) {
            unsigned int e4 = (tri >> (4 * s)) & 0xFu;
            bool valid = (e4 != 0xFu);
            unsigned int e = valid ? e4 : 0u;
            if (s == 0) mask0 = valid;
            if (s == 3) mask1 = valid;
            int a = (int)((EA_PACK >> (4 * e)) & 0xFu);
            int b = (int)((EB_PACK >> (4 * e)) & 0xFu);
            float va = tv[a], vb = tv[b];
            float den = vb - va;
            float dsafe = (fabsf(den) > 1e-8f) ? den : 1.0f;
            // fast reciprocal (~1 ulp) instead of precise divide sequence
            float tt = (-va) * __builtin_amdgcn_rcpf(dsafe);
            tt = fminf(fmaxf(tt, 0.0f), 1.0f);
            float vm = valid ? (1.0f / 63.0f) : 0.0f;   // fold /scale and *valid
            float px = tpx[a] + tt * (tpx[b] - tpx[a]);
            float py = tpy[a] + tt * (tpy[b] - tpy[a]);
            float pz = tpz[a] + tt * (tpz[b] - tpz[a]);
            verts[s * 3 + 0] = (px - 1.0f) * vm;
            verts[s * 3 + 1] = (py - 1.0f) * vm;
            verts[s * 3 + 2] = (pz - 1.0f) * vm;
        }

        // stage verts AoS: 9 x b64, dword-stride 18 between lanes (uniform banks)
        #pragma unroll
        for (int s2 = 0; s2 < 9; ++s2)
            *reinterpret_cast<float2*>(&ldsv[tid * 18 + 2 * s2]) =
                make_float2(verts[2 * s2], verts[2 * s2 + 1]);
        ldsm[tid] = make_float2(mask0 ? 1.0f : 0.0f, mask1 ? 1.0f : 0.0f);
    }

    // ---- tris: direct float4 arange fill, non-temporal (streaming) ----
    {
        float* ot = out + (size_t)TRIS_OFF_F + (size_t)base * 6;
        float fb = (float)(6 * base);          // exact (< 2^24)
        if (full) {
            f4v* ot4 = reinterpret_cast<f4v*>(ot);   // 384 f4v per block
            float v0 = fb + (float)(4 * tid);
            f4v w0 = { v0, v0 + 1.f, v0 + 2.f, v0 + 3.f };
            __builtin_nontemporal_store(w0, &ot4[tid]);
            if (tid < 128) {
                float v1 = fb + (float)(4 * (NTPB + tid));
                f4v w1 = { v1, v1 + 1.f, v1 + 2.f, v1 + 3.f };
                __builtin_nontemporal_store(w1, &ot4[NTPB + tid]);
            }
        } else {
            for (int p = tid; p < nv * 6; p += NTPB)
                ot[p] = fb + (float)p;
        }
    }

    __syncthreads();

    if (full) {
        // ---- verts: 1152 f4v per block, b128 LDS reads + nt dwordx4 stores ----
        const f4v* lv4 = reinterpret_cast<const f4v*>(ldsv);
        f4v* ov4 = reinterpret_cast<f4v*>(out + (size_t)base * 18);
        #pragma unroll
        for (int k = 0; k < 4; ++k)
            __builtin_nontemporal_store(lv4[k * NTPB + tid], &ov4[k * NTPB + tid]);
        if (tid < 128)
            __builtin_nontemporal_store(lv4[4 * NTPB + tid], &ov4[4 * NTPB + tid]);

        // ---- mask: 128 f4v per block ----
        f4v* om4 = reinterpret_cast<f4v*>(out + (size_t)MASK_OFF_F + (size_t)base * 2);
        if (tid < 128)
            __builtin_nontemporal_store(reinterpret_cast<const f4v*>(ldsm)[tid],
                                        &om4[tid]);
    } else {
        // partial tail block (nv = 134): scalar fallback, negligible cost
        float* ov = out + (size_t)base * 18;
        for (int p = tid; p < nv * 18; p += NTPB)
            ov[p] = ldsv[p];
        float2* om = reinterpret_cast<float2*>(out + (size_t)MASK_OFF_F + (size_t)base * 2);
        if (tid < nv)
            om[tid] = ldsm[tid];
    }
}

extern "C" void kernel_launch(void* const* d_in, const int* in_sizes, int n_in,
                              void* d_out, int out_size, void* d_ws, size_t ws_size,
                              hipStream_t stream) {
    const float* grid   = (const float*)d_in[0];
    const float* deform = (const float*)d_in[1];
    float* out = (float*)d_out;

    int blocks = (NTET + NTPB - 1) / NTPB;   // 6437
    mc_kernel<<<blocks, NTPB, 0, stream>>>(grid, deform, out);
}

// Round 9
// 32.646 us; speedup vs baseline: 1.2766x; 1.2766x over previous
//
#include <hip/hip_runtime.h>
#include <stdint.h>

// ---------------- problem constants ----------------
#define DIM   64
#define VPA   65                      // voxels per axis = DIM+1
#define NVOX  (VPA*VPA*VPA)           // 274625
#define NTET  (6*NVOX)                // 1647750 tets (M)
// output is FLOAT32, concatenated flat: verts | tris | mask (f32 element offsets)
#define TRIS_OFF_F  29659500          // NTET*18
#define MASK_OFF_F  39546000          // NTET*18 + NTET*6
#define NTPB 256                      // tets per block (= threads per block)
#define NWG  6437                     // (NTET + NTPB - 1) / NTPB
#define NXCD 8

// marching-tets case table, nibble packed: slot s in bits [4s,4s+4), 0xF == -1
__constant__ unsigned int c_TRIP[16] = {
    0xFFFFFFu, // 0: none
    0xFFF210u, // 1: 0,1,2
    0xFFF340u, // 2: 0,4,3
    0x341421u, // 3: 1,2,4, 1,4,3
    0xFFF531u, // 4: 1,3,5
    0x250530u, // 5: 0,3,5, 0,5,2
    0x150540u, // 6: 0,4,5, 0,5,1
    0xFFF542u, // 7: 2,4,5
    0xFFF452u, // 8: 2,5,4
    0x510450u, // 9: 0,5,4, 0,1,5
    0x520350u, //10: 0,5,3, 0,2,5
    0xFFF351u, //11: 1,5,3
    0x431241u, //12: 1,4,2, 1,3,4
    0xFFF430u, //13: 0,3,4
    0xFFF120u, //14: 0,2,1
    0xFFFFFFu  //15: none
};
// tet corner ids (voxel corner 0..7), nibble packed per tet (TETS rows)
__constant__ unsigned short c_TETP[6] = {
    0x6210u, 0x6320u, 0x6730u, 0x6470u, 0x6540u, 0x6150u
};
// edge endpoint tables, nibble packed: EDGE_A={0,0,0,1,1,2}, EDGE_B={1,2,3,2,3,3}
#define EA_PACK 0x211000u
#define EB_PACK 0x332321u
// voxel corner offset bitmasks: x set for corners {1,2,5,6}; y {2,3,6,7}; z {4,5,6,7}
#define OFFX_MASK 0x66u
#define OFFY_MASK 0xCCu
#define OFFZ_MASK 0xF0u

__global__ __launch_bounds__(256) void mc_kernel(
    const float* __restrict__ grid,
    const float* __restrict__ deform,
    float* __restrict__ out)
{
    // AoS staging: ldsv[t*18 + j] == output float (base*18 + t*18 + j)
    __shared__ __align__(16) float  ldsv[NTPB * 18];   // 18432 B
    __shared__ __align__(16) float2 ldsm[NTPB];        //  2048 B

    const int tid  = threadIdx.x;

    // Bijective XCD-chunked swizzle (m204 form): XCD x processes a CONTIGUOUS
    // tet range so its L2 read working set is ~0.5 MB (survives write streaming).
    int gen;
    {
        const int q = NWG >> 3, r = NWG & 7;          // 804, 5
        int xcd = blockIdx.x & (NXCD - 1);
        int idx = blockIdx.x >> 3;
        gen = (xcd < r ? xcd * (q + 1) : r * (q + 1) + (xcd - r) * q) + idx;
    }

    const int base = gen * NTPB;
    const int m    = base + tid;
    const int nv   = min(NTPB, NTET - base);   // valid tets in this block
    const bool full = (nv == NTPB);            // block-uniform

    if (m < NTET) {
        int v = m / 6;
        int t = m - v * 6;
        int iz = v % VPA;
        int tmp = v / VPA;
        int iy = tmp % VPA;
        int ix = tmp / VPA;

        // gather 4 tet corners: value + deformed position
        float tv[4];
        float tpx[4], tpy[4], tpz[4];
        unsigned int tet = c_TETP[t];
        #pragma unroll
        for (int c = 0; c < 4; ++c) {
            unsigned int corner = (tet >> (4 * c)) & 0xFu;
            int px = ix + (int)((OFFX_MASK >> corner) & 1u);
            int py = iy + (int)((OFFY_MASK >> corner) & 1u);
            int pz = iz + (int)((OFFZ_MASK >> corner) & 1u);
            // padded coords px,py,pz in [0,65]; interior iff 1..64
            bool interior = ((unsigned)(px - 1) < (unsigned)DIM) &
                            ((unsigned)(py - 1) < (unsigned)DIM) &
                            ((unsigned)(pz - 1) < (unsigned)DIM);
            float val = 1.0f;               // iso + 1 pad value
            float dx = 0.f, dy = 0.f, dz = 0.f;
            if (interior) {
                int gi = ((px - 1) * DIM + (py - 1)) * DIM + (pz - 1);
                val = grid[gi];
                const float* d = deform + 3 * (size_t)gi;
                dx = d[0]; dy = d[1]; dz = d[2];
            }
            tv[c]  = val;
            tpx[c] = (float)px + dx;
            tpy[c] = (float)py + dy;
            tpz[c] = (float)pz + dz;
        }

        int code = (tv[0] > 0.f ? 1 : 0) | (tv[1] > 0.f ? 2 : 0) |
                   (tv[2] > 0.f ? 4 : 0) | (tv[3] > 0.f ? 8 : 0);
        unsigned int tri = c_TRIP[code];

        float verts[18];
        bool mask0 = false, mask1 = false;
        #pragma unroll
        for (int s = 0; s < 6; ++s) {
            unsigned int e4 = (tri >> (4 * s)) & 0xFu;
            bool valid = (e4 != 0xFu);
            unsigned int e = valid ? e4 : 0u;
            if (s == 0) mask0 = valid;
            if (s == 3) mask1 = valid;
            int a = (int)((EA_PACK >> (4 * e)) & 0xFu);
            int b = (int)((EB_PACK >> (4 * e)) & 0xFu);
            float va = tv[a], vb = tv[b];
            float den = vb - va;
            float dsafe = (fabsf(den) > 1e-8f) ? den : 1.0f;
            // fast reciprocal (~1 ulp) instead of precise divide sequence
            float tt = (-va) * __builtin_amdgcn_rcpf(dsafe);
            tt = fminf(fmaxf(tt, 0.0f), 1.0f);
            float vm = valid ? (1.0f / 63.0f) : 0.0f;   // fold /scale and *valid
            float px = tpx[a] + tt * (tpx[b] - tpx[a]);
            float py = tpy[a] + tt * (tpy[b] - tpy[a]);
            float pz = tpz[a] + tt * (tpz[b] - tpz[a]);
            verts[s * 3 + 0] = (px - 1.0f) * vm;
            verts[s * 3 + 1] = (py - 1.0f) * vm;
            verts[s * 3 + 2] = (pz - 1.0f) * vm;
        }

        // stage verts AoS: 9 x b64, dword-stride 18 between lanes (uniform banks)
        #pragma unroll
        for (int s2 = 0; s2 < 9; ++s2)
            *reinterpret_cast<float2*>(&ldsv[tid * 18 + 2 * s2]) =
                make_float2(verts[2 * s2], verts[2 * s2 + 1]);
        ldsm[tid] = make_float2(mask0 ? 1.0f : 0.0f, mask1 ? 1.0f : 0.0f);
    }

    // ---- tris: direct float4 arange fill (no LDS needed) ----
    {
        float* ot = out + (size_t)TRIS_OFF_F + (size_t)base * 6;
        float fb = (float)(6 * base);          // exact (< 2^24)
        if (full) {
            float4* ot4 = reinterpret_cast<float4*>(ot);   // 384 float4 per block
            float v0 = fb + (float)(4 * tid);
            ot4[tid] = make_float4(v0, v0 + 1.f, v0 + 2.f, v0 + 3.f);
            if (tid < 128) {
                float v1 = fb + (float)(4 * (NTPB + tid));
                ot4[NTPB + tid] = make_float4(v1, v1 + 1.f, v1 + 2.f, v1 + 3.f);
            }
        } else {
            for (int p = tid; p < nv * 6; p += NTPB)
                ot[p] = fb + (float)p;
        }
    }

    __syncthreads();

    if (full) {
        // ---- verts: 1152 float4 per block, b128 LDS reads + dwordx4 stores ----
        const float4* lv4 = reinterpret_cast<const float4*>(ldsv);
        float4* ov4 = reinterpret_cast<float4*>(out + (size_t)base * 18);
        #pragma unroll
        for (int k = 0; k < 4; ++k)
            ov4[k * NTPB + tid] = lv4[k * NTPB + tid];
        if (tid < 128)
            ov4[4 * NTPB + tid] = lv4[4 * NTPB + tid];

        // ---- mask: 128 float4 per block ----
        float4* om4 = reinterpret_cast<float4*>(out + (size_t)MASK_OFF_F + (size_t)base * 2);
        if (tid < 128)
            om4[tid] = reinterpret_cast<const float4*>(ldsm)[tid];
    } else {
        // partial tail block (nv = 134): scalar fallback, negligible cost
        float* ov = out + (size_t)base * 18;
        for (int p = tid; p < nv * 18; p += NTPB)
            ov[p] = ldsv[p];
        float2* om = reinterpret_cast<float2*>(out + (size_t)MASK_OFF_F + (size_t)base * 2);
        if (tid < nv)
            om[tid] = ldsm[tid];
    }
}

extern "C" void kernel_launch(void* const* d_in, const int* in_sizes, int n_in,
                              void* d_out, int out_size, void* d_ws, size_t ws_size,
                              hipStream_t stream) {
    const float* grid   = (const float*)d_in[0];
    const float* deform = (const float*)d_in[1];
    float* out = (float*)d_out;

    mc_kernel<<<NWG, NTPB, 0, stream>>>(grid, deform, out);
}